// Round 6
// baseline (313.755 us; speedup 1.0000x reference)
//
#include <hip/hip_runtime.h>
#include <stdint.h>

// Problem constants
#define B_SZ 1024
#define Z_SZ 32768
#define D_SZ 128
#define NZ   64                 // z chunks (split-Z) -> grid 16x64 = 1024 blocks = 4/CU
#define CZ   (Z_SZ / NZ)        // 512 z per chunk
#define TZ   64                 // z per inner tile
#define ITERS (CZ / TZ)         // 8
#define TBLK 64                 // batch rows per block (4 waves x 16)
#define WROWS 16                // batch rows per wave

// LDS: only the per-wave P tile remains (tables are L2/L3-resident -> no staging).
#define SP_STRIDE    72         // 16 x 72 bf16 per wave (P tile), 144B rows
#define ST_STRIDE    136        // prep transpose staging rows hold 128 elems -> stride >= 128

#define NB_TAB  (Z_SZ / 64)     // 512 blocks build bf16 tables

// Workspace layout (float offsets)
#define WS_O   0                              // [NZ][B][D]  (33.5 MB)
#define WS_M   (NZ * B_SZ * D_SZ)             // [NZ][B]
#define WS_L   (WS_M + NZ * B_SZ)
#define WS_C   (WS_L + NZ * B_SZ)
#define WS_TAB (WS_C + NZ * B_SZ)             // embR [Z][D] bf16, embT [D][Z] bf16

typedef short bf16x8 __attribute__((ext_vector_type(8)));
typedef float f32x4  __attribute__((ext_vector_type(4)));

#if __has_builtin(__builtin_amdgcn_exp2f)
#define EXP2F(x) __builtin_amdgcn_exp2f(x)
#else
#define EXP2F(x) exp2f(x)
#endif

__device__ __forceinline__ unsigned short f2bf(float f) {
    union { float f; uint32_t u; } v; v.f = f;
    uint32_t u = v.u;
    u = (u + 0x7FFFu + ((u >> 16) & 1u)) >> 16;   // RNE truncate to bf16
    return (unsigned short)u;
}

// ---------------------------------------------------------------------------
// Prep: emb f32 [Z][D] -> bf16 embR [Z][D] and embT [D][Z]  (one block / 64 z)
// ---------------------------------------------------------------------------
__global__ __launch_bounds__(256) void prep(
    const float*    __restrict__ emb,
    unsigned short* __restrict__ embR,
    unsigned short* __restrict__ embT)
{
    __shared__ __align__(16) unsigned short st[64 * ST_STRIDE];
    const int z0 = blockIdx.x * 64;
    const int t  = threadIdx.x;
    {
        const int r = t >> 2, q = t & 3;
        const float* src = emb + (size_t)(z0 + r) * D_SZ + q * 32;
        unsigned short* dR = embR + (size_t)(z0 + r) * D_SZ + q * 32;
        unsigned short* dL = st + r * ST_STRIDE + q * 32;
#pragma unroll
        for (int u = 0; u < 8; ++u) {
            float4 x = *(const float4*)(src + 4 * u);
            ushort4 h;
            h.x = f2bf(x.x); h.y = f2bf(x.y); h.z = f2bf(x.z); h.w = f2bf(x.w);
            *(ushort4*)(dR + 4 * u) = h;
            *(ushort4*)(dL + 4 * u) = h;
        }
    }
    __syncthreads();
    {
        const int lane = t & 63, w = t >> 6;
#pragma unroll
        for (int i = 0; i < 4; ++i) {
            const int d = w * 32 + i * 8 + (lane >> 3);   // 0..127
            const int c = lane & 7;                       // 8-z chunk
            bf16x8 v;
#pragma unroll
            for (int k = 0; k < 8; ++k) v[k] = (short)st[(c * 8 + k) * ST_STRIDE + d];
            *(bf16x8*)(embT + (size_t)d * Z_SZ + z0 + c * 8) = v;
        }
    }
}

// ---------------------------------------------------------------------------
// attn_part, barrier-free: operand fragments straight from L2-resident tables.
//   GEMM1: sfr[nt] = mfma(embR_frag, ctx)  -> lane holds S[b=l15][z'=16nt+4quad+r]
//   softmax: in-lane tree + 2 shfl_xor; T13 defer-max (THR=8)
//   GEMM2 (O^T): acc2[nt2] = mfma(embT_frag, P^T) -> lane holds O[d][b=l15]
//   LDS: per-wave s_P only -> no __syncthreads anywhere; waves free-run.
// ---------------------------------------------------------------------------
__global__ __launch_bounds__(256, 4) void attn_part(
    const int*            __restrict__ zs,
    const float*          __restrict__ ctx,
    const unsigned short* __restrict__ embR,
    const unsigned short* __restrict__ embT,
    float*                __restrict__ ws)
{
    __shared__ __align__(16) unsigned short s_P[4 * WROWS * SP_STRIDE];   // 9216 B

    const int tid  = threadIdx.x;
    const int wave = tid >> 6;
    const int lane = tid & 63;
    const int l15  = lane & 15;
    const int quad = lane >> 4;

    const int bg     = blockIdx.x;            // 0..15 batch group
    const int ch     = blockIdx.y;            // 0..63 z-chunk
    const int z_base = ch * CZ;
    const int wb0    = bg * TBLK + wave * WROWS;  // first batch row of this wave
    const int brow   = wb0 + l15;                 // this lane's batch row

    const int* zrow = zs + (size_t)brow * Z_SZ + quad * 4;   // lane's mask base

    // ---- ctx B-fragments, scaled by log2(e)/sqrt(D) (base-2 softmax), in regs ----
    bf16x8 afrag[4];
    {
        const float scale = (float)(1.4426950408889634 * 0.08838834764831845);
        const float* crow = ctx + (size_t)brow * D_SZ;
#pragma unroll
        for (int ks = 0; ks < 4; ++ks) {
            const float* p = crow + ks * 32 + quad * 8;
            float4 x0 = *(const float4*)(p);
            float4 x1 = *(const float4*)(p + 4);
            bf16x8 a;
            a[0] = (short)f2bf(x0.x * scale); a[1] = (short)f2bf(x0.y * scale);
            a[2] = (short)f2bf(x0.z * scale); a[3] = (short)f2bf(x0.w * scale);
            a[4] = (short)f2bf(x1.x * scale); a[5] = (short)f2bf(x1.y * scale);
            a[6] = (short)f2bf(x1.z * scale); a[7] = (short)f2bf(x1.w * scale);
            afrag[ks] = a;
        }
    }

    // ---- per-lane online-softmax state for row b = brow (replicated across quads) ----
    float m_s = -1e30f, l_s = 0.f;
    int   cnt = 0;      // per-lane partial count; reduced at epilogue
    f32x4 acc2[8];
#pragma unroll
    for (int n = 0; n < 8; ++n) { acc2[n][0]=0.f; acc2[n][1]=0.f; acc2[n][2]=0.f; acc2[n][3]=0.f; }

    for (int it = 0; it < ITERS; ++it) {
        const int z0 = z_base + it * TZ;

        // ---- mask int4 loads (needed after GEMM1; issue first, latency hides) ----
        int4 mc[4];
#pragma unroll
        for (int nt = 0; nt < 4; ++nt) mc[nt] = *(const int4*)(zrow + z0 + nt * 16);

        // ---- GEMM1: A-frag straight from embR (L2-hot); lane reads its own row ----
        f32x4 sfr[4];
#pragma unroll
        for (int nt = 0; nt < 4; ++nt) {
            f32x4 c; c[0]=0.f; c[1]=0.f; c[2]=0.f; c[3]=0.f;
            const unsigned short* er = embR + (size_t)(z0 + nt * 16 + l15) * D_SZ + quad * 8;
#pragma unroll
            for (int ks = 0; ks < 4; ++ks) {
                bf16x8 ef = *(const bf16x8*)(er + ks * 32);
                c = __builtin_amdgcn_mfma_f32_16x16x32_bf16(ef, afrag[ks], c, 0, 0, 0);
            }
            sfr[nt] = c;
        }

        // ---- mask bits straight from int4 components: z' = 16nt + 4quad + r ----
        int bit[4][4];
#pragma unroll
        for (int nt = 0; nt < 4; ++nt) {
            bit[nt][0] = (mc[nt].x > 0) ? 1 : 0;
            bit[nt][1] = (mc[nt].y > 0) ? 1 : 0;
            bit[nt][2] = (mc[nt].z > 0) ? 1 : 0;
            bit[nt][3] = (mc[nt].w > 0) ? 1 : 0;
            cnt += bit[nt][0] + bit[nt][1] + bit[nt][2] + bit[nt][3];
        }

        // ---- masked max: in-lane tree + 2 cross-quad shuffles ----
        float tm = -1e30f;
#pragma unroll
        for (int nt = 0; nt < 4; ++nt) {
            float a0 = bit[nt][0] ? sfr[nt][0] : -1e30f;
            float a1 = bit[nt][1] ? sfr[nt][1] : -1e30f;
            float a2 = bit[nt][2] ? sfr[nt][2] : -1e30f;
            float a3 = bit[nt][3] ? sfr[nt][3] : -1e30f;
            tm = fmaxf(tm, fmaxf(fmaxf(a0, a1), fmaxf(a2, a3)));
        }
        tm = fmaxf(tm, __shfl_xor(tm, 16));
        tm = fmaxf(tm, __shfl_xor(tm, 32));

        // ---- T13 defer-max: only rescale when the max moved by > 8 (base-2) ----
        if (__any(tm > m_s + 8.f)) {
            float mnew = fmaxf(m_s, tm);
            float al = EXP2F(m_s - mnew);     // first active tile: exp2(-huge) = 0
            m_s = mnew;
            l_s *= al;
#pragma unroll
            for (int n = 0; n < 8; ++n) acc2[n] *= al;
        }

        // ---- P = mask ? 2^(S - m) : 0 ; pack to per-wave LDS (B-frag route) ----
        unsigned short* pwv = s_P + wave * (WROWS * SP_STRIDE) + l15 * SP_STRIDE + quad * 4;
        float ps = 0.f;
#pragma unroll
        for (int nt = 0; nt < 4; ++nt) {
            float p0 = bit[nt][0] ? EXP2F(sfr[nt][0] - m_s) : 0.f;
            float p1 = bit[nt][1] ? EXP2F(sfr[nt][1] - m_s) : 0.f;
            float p2 = bit[nt][2] ? EXP2F(sfr[nt][2] - m_s) : 0.f;
            float p3 = bit[nt][3] ? EXP2F(sfr[nt][3] - m_s) : 0.f;
            ps += (p0 + p1) + (p2 + p3);
            ushort4 h;
            h.x = f2bf(p0); h.y = f2bf(p1); h.z = f2bf(p2); h.w = f2bf(p3);
            *(ushort4*)(pwv + nt * 16) = h;   // s_P[b=l15][z' = 16nt + 4quad + 0..3]
        }
        ps += __shfl_xor(ps, 16);
        ps += __shfl_xor(ps, 32);
        l_s += ps;

        // ---- GEMM2 (O^T): acc2[nt2] += embT_frag @ P^T  (K = 64 via two slices) ----
        // same-wave DS ordering guarantees the P writes above are visible to these reads
        const unsigned short* pb = s_P + wave * (WROWS * SP_STRIDE) + l15 * SP_STRIDE + quad * 8;
        bf16x8 pA0 = *(const bf16x8*)(pb);        // P[b=l15][z = quad*8 + j], z<32
        bf16x8 pA1 = *(const bf16x8*)(pb + 32);   // z >= 32
#pragma unroll
        for (int nt2 = 0; nt2 < 8; ++nt2) {
            const unsigned short* te = embT + (size_t)(nt2 * 16 + l15) * Z_SZ + z0 + quad * 8;
            bf16x8 e0 = *(const bf16x8*)(te);
            bf16x8 e1 = *(const bf16x8*)(te + 32);
            acc2[nt2] = __builtin_amdgcn_mfma_f32_16x16x32_bf16(e0, pA0, acc2[nt2], 0, 0, 0);
            acc2[nt2] = __builtin_amdgcn_mfma_f32_16x16x32_bf16(e1, pA1, acc2[nt2], 0, 0, 0);
        }
    }

    // ---- epilogue: O rows are lane-local -> 8 vector stores; reduce cnt across quads ----
    {
        float* orow = ws + WS_O + ((size_t)ch * B_SZ + brow) * D_SZ;
#pragma unroll
        for (int nt2 = 0; nt2 < 8; ++nt2) {
            *(f32x4*)(orow + nt2 * 16 + quad * 4) = acc2[nt2];
        }
    }
    cnt += __shfl_xor(cnt, 16);
    cnt += __shfl_xor(cnt, 32);
    if (lane < 16) {
        ws[WS_M + ch * B_SZ + brow] = m_s;
        ws[WS_L + ch * B_SZ + brow] = l_s;
        ws[WS_C + ch * B_SZ + brow] = (float)cnt;
    }
}

__global__ __launch_bounds__(128) void attn_reduce(
    const float* __restrict__ ws, float* __restrict__ out)
{
    const int b = blockIdx.x;
    const int d = threadIdx.x;
    const float* mP = ws + WS_M;
    const float* lP = ws + WS_L;
    const float* cP = ws + WS_C;

    float M = -1e30f;
#pragma unroll
    for (int c = 0; c < NZ; ++c) M = fmaxf(M, mP[c * B_SZ + b]);

    float L = 0.f, C = 0.f, acc = 0.f;
#pragma unroll
    for (int c = 0; c < NZ; ++c) {
        float w = EXP2F(mP[c * B_SZ + b] - M);
        L += lP[c * B_SZ + b] * w;
        C += cP[c * B_SZ + b];
        acc += ws[WS_O + ((size_t)c * B_SZ + b) * D_SZ + d] * w;
    }
    float cntv = fmaxf(C, 1.0f);
    out[(size_t)b * D_SZ + d] = (L > 0.f) ? acc / (L * cntv) : 0.f;
}

extern "C" void kernel_launch(void* const* d_in, const int* in_sizes, int n_in,
                              void* d_out, int out_size, void* d_ws, size_t ws_size,
                              hipStream_t stream) {
    (void)in_sizes; (void)n_in; (void)out_size; (void)ws_size;
    const int*   zs  = (const int*)  d_in[0];
    const float* ctx = (const float*)d_in[1];
    const float* emb = (const float*)d_in[2];
    float* out = (float*)d_out;
    float* ws  = (float*)d_ws;

    unsigned short* embR = (unsigned short*)(ws + WS_TAB);
    unsigned short* embT = embR + (size_t)Z_SZ * D_SZ;

    prep<<<NB_TAB, 256, 0, stream>>>(emb, embR, embT);

    dim3 grid1(B_SZ / TBLK, NZ);   // (16, 64): 1024 blocks = 4/CU; x-neighbors share a chunk
    attn_part<<<grid1, 256, 0, stream>>>(zs, ctx, embR, embT, ws);
    attn_reduce<<<B_SZ, 128, 0, stream>>>(ws, out);
}

// Round 7
// 247.887 us; speedup vs baseline: 1.2657x; 1.2657x over previous
//
#include <hip/hip_runtime.h>
#include <stdint.h>

// Problem constants
#define B_SZ 1024
#define Z_SZ 32768
#define D_SZ 128
#define NZ   64                 // z chunks (split-Z)
#define CZ   (Z_SZ / NZ)        // 512 z per chunk
#define TZ   64                 // z per inner tile
#define ITERS (CZ / TZ)         // 8
#define TBLK 128                // batch rows per block (8 waves x 16)
#define NWAVE 8
#define WROWS 16                // batch rows per wave

// LDS strides (elements). Row byte-strides must be 16B multiples for ds_read_b128,
// and every stride must be >= the row's element count (128 for d-rows, 64 for z-rows).
#define SEMB_STRIDE  136        // 64 x 136 bf16 (row-major emb tile), 272B rows
#define SEMBT_STRIDE 72         // 128 x 72 bf16 (transposed emb tile), 144B rows
#define SP_STRIDE    72         // 16 x 72 bf16 per wave (P tile), 144B rows
#define ST_STRIDE    136        // prep transpose staging rows hold 128 elems -> stride >= 128

#define NB_TAB  (Z_SZ / 64)     // 512 blocks build bf16 tables

// Workspace layout (float offsets)
#define WS_O   0                              // [NZ][B][D]  (33.5 MB)
#define WS_M   (NZ * B_SZ * D_SZ)             // [NZ][B]
#define WS_L   (WS_M + NZ * B_SZ)
#define WS_C   (WS_L + NZ * B_SZ)
#define WS_TAB (WS_C + NZ * B_SZ)             // embR [Z][D] bf16, embT [D][Z] bf16

typedef short bf16x8 __attribute__((ext_vector_type(8)));
typedef float f32x4  __attribute__((ext_vector_type(4)));

#if __has_builtin(__builtin_amdgcn_exp2f)
#define EXP2F(x) __builtin_amdgcn_exp2f(x)
#else
#define EXP2F(x) exp2f(x)
#endif

__device__ __forceinline__ unsigned short f2bf(float f) {
    union { float f; uint32_t u; } v; v.f = f;
    uint32_t u = v.u;
    u = (u + 0x7FFFu + ((u >> 16) & 1u)) >> 16;   // RNE truncate to bf16
    return (unsigned short)u;
}

// ---------------------------------------------------------------------------
// Prep: emb f32 [Z][D] -> bf16 embR [Z][D] and embT [D][Z]  (one block / 64 z)
// ---------------------------------------------------------------------------
__global__ __launch_bounds__(256) void prep(
    const float*    __restrict__ emb,
    unsigned short* __restrict__ embR,
    unsigned short* __restrict__ embT)
{
    __shared__ __align__(16) unsigned short st[64 * ST_STRIDE];
    const int z0 = blockIdx.x * 64;
    const int t  = threadIdx.x;
    {
        const int r = t >> 2, q = t & 3;
        const float* src = emb + (size_t)(z0 + r) * D_SZ + q * 32;
        unsigned short* dR = embR + (size_t)(z0 + r) * D_SZ + q * 32;
        unsigned short* dL = st + r * ST_STRIDE + q * 32;
#pragma unroll
        for (int u = 0; u < 8; ++u) {
            float4 x = *(const float4*)(src + 4 * u);
            ushort4 h;
            h.x = f2bf(x.x); h.y = f2bf(x.y); h.z = f2bf(x.z); h.w = f2bf(x.w);
            *(ushort4*)(dR + 4 * u) = h;
            *(ushort4*)(dL + 4 * u) = h;
        }
    }
    __syncthreads();
    {
        const int lane = t & 63, w = t >> 6;
#pragma unroll
        for (int i = 0; i < 4; ++i) {
            const int d = w * 32 + i * 8 + (lane >> 3);   // 0..127
            const int c = lane & 7;                       // 8-z chunk
            bf16x8 v;
#pragma unroll
            for (int k = 0; k < 8; ++k) v[k] = (short)st[(c * 8 + k) * ST_STRIDE + d];
            *(bf16x8*)(embT + (size_t)d * Z_SZ + z0 + c * 8) = v;
        }
    }
}

// ---------------------------------------------------------------------------
// attn_part, 8-wave blocks: one staged 64-z tile feeds 8 waves (128 batch rows).
//   GEMM1: sfr[nt] = mfma(emb_rows, ctx)   -> lane holds S[b=l15][z'=16nt+4quad+r]
//   softmax: in-lane tree + 2 shfl_xor; T13 defer-max (THR=8)
//   GEMM2 (O^T): acc2[nt2] = mfma(embT_rows, P^T) -> lane holds O[d][b=l15]
//   T14 prefetch: next tile's fragments + mask int4s load during current compute.
// ---------------------------------------------------------------------------
__global__ __launch_bounds__(512, 4) void attn_part(
    const int*            __restrict__ zs,
    const float*          __restrict__ ctx,
    const unsigned short* __restrict__ embR,
    const unsigned short* __restrict__ embT,
    float*                __restrict__ ws)
{
    __shared__ __align__(16) unsigned short s_emb [TZ   * SEMB_STRIDE];      // 17408 B
    __shared__ __align__(16) unsigned short s_embT[D_SZ * SEMBT_STRIDE];     // 18432 B
    __shared__ __align__(16) unsigned short s_P   [NWAVE * WROWS * SP_STRIDE];// 18432 B

    const int tid  = threadIdx.x;
    const int wave = tid >> 6;
    const int lane = tid & 63;
    const int l15  = lane & 15;
    const int quad = lane >> 4;

    const int bg     = blockIdx.x;            // 0..7 batch group
    const int ch     = blockIdx.y;            // 0..63 z-chunk
    const int z_base = ch * CZ;
    const int wb0    = bg * TBLK + wave * WROWS;  // first batch row of this wave
    const int brow   = wb0 + l15;                 // this lane's batch row

    // staging thread mappings (512 threads, 32B each per tile)
    const int srow = tid >> 3, sseg = tid & 7;   // row tile: row, 16-elem seg pair
    const int sd   = tid >> 2, szz  = tid & 3;   // transposed tile: d-row, 16-z seg pair

    const int* zrow = zs + (size_t)brow * Z_SZ + quad * 4;   // lane's mask base

    // ---- ctx B-fragments, scaled by log2(e)/sqrt(D) (base-2 softmax), in regs ----
    bf16x8 afrag[4];
    {
        const float scale = (float)(1.4426950408889634 * 0.08838834764831845);
        const float* crow = ctx + (size_t)brow * D_SZ;
#pragma unroll
        for (int ks = 0; ks < 4; ++ks) {
            const float* p = crow + ks * 32 + quad * 8;
            float4 x0 = *(const float4*)(p);
            float4 x1 = *(const float4*)(p + 4);
            bf16x8 a;
            a[0] = (short)f2bf(x0.x * scale); a[1] = (short)f2bf(x0.y * scale);
            a[2] = (short)f2bf(x0.z * scale); a[3] = (short)f2bf(x0.w * scale);
            a[4] = (short)f2bf(x1.x * scale); a[5] = (short)f2bf(x1.y * scale);
            a[6] = (short)f2bf(x1.z * scale); a[7] = (short)f2bf(x1.w * scale);
            afrag[ks] = a;
        }
    }

    // ---- per-lane online-softmax state for row b = brow (replicated across quads) ----
    float m_s = -1e30f, l_s = 0.f;
    int   cnt = 0;      // per-lane partial count; reduced at epilogue
    f32x4 acc2[8];
#pragma unroll
    for (int n = 0; n < 8; ++n) { acc2[n][0]=0.f; acc2[n][1]=0.f; acc2[n][2]=0.f; acc2[n][3]=0.f; }

    // ---- T14 async-STAGE registers: next tile's fragments (32B each) + mask int4s ----
    bf16x8 rA0, rA1, rT0, rT1;
    int4   mc[4], mn[4];
    {
        const unsigned short* srcR = embR + (size_t)(z_base + srow) * D_SZ + sseg * 16;
        const unsigned short* srcT = embT + (size_t)sd * Z_SZ + z_base + szz * 16;
        rA0 = *(const bf16x8*)(srcR);     rA1 = *(const bf16x8*)(srcR + 8);
        rT0 = *(const bf16x8*)(srcT);     rT1 = *(const bf16x8*)(srcT + 8);
#pragma unroll
        for (int nt = 0; nt < 4; ++nt) mc[nt] = *(const int4*)(zrow + z_base + nt * 16);
    }

    for (int it = 0; it < ITERS; ++it) {
        __syncthreads();   // previous tile's LDS reads complete

        // ---- write staged registers to LDS ----
        {
            unsigned short* dst = s_emb + srow * SEMB_STRIDE + sseg * 16;
            *(bf16x8*)(dst)     = rA0;
            *(bf16x8*)(dst + 8) = rA1;
        }
        {
            unsigned short* dst = s_embT + sd * SEMBT_STRIDE + szz * 16;
            *(bf16x8*)(dst)     = rT0;
            *(bf16x8*)(dst + 8) = rT1;
        }

        __syncthreads();   // staging visible

        // ---- issue next tile's global loads; latency hides under MFMA/softmax ----
        if (it + 1 < ITERS) {
            const int z0n = z_base + (it + 1) * TZ;
            const unsigned short* srcR = embR + (size_t)(z0n + srow) * D_SZ + sseg * 16;
            const unsigned short* srcT = embT + (size_t)sd * Z_SZ + z0n + szz * 16;
            rA0 = *(const bf16x8*)(srcR);     rA1 = *(const bf16x8*)(srcR + 8);
            rT0 = *(const bf16x8*)(srcT);     rT1 = *(const bf16x8*)(srcT + 8);
#pragma unroll
            for (int nt = 0; nt < 4; ++nt) mn[nt] = *(const int4*)(zrow + z0n + nt * 16);
        }

        // ---- GEMM1: S^T tiles; lane gets S[b=l15][z' = nt*16 + quad*4 + r] ----
        f32x4 sfr[4];
#pragma unroll
        for (int nt = 0; nt < 4; ++nt) {
            f32x4 c; c[0]=0.f; c[1]=0.f; c[2]=0.f; c[3]=0.f;
            const unsigned short* bb = s_emb + (nt * 16 + l15) * SEMB_STRIDE + quad * 8;
#pragma unroll
            for (int ks = 0; ks < 4; ++ks) {
                bf16x8 ef = *(const bf16x8*)(bb + ks * 32);
                c = __builtin_amdgcn_mfma_f32_16x16x32_bf16(ef, afrag[ks], c, 0, 0, 0);
            }
            sfr[nt] = c;
        }

        // ---- mask bits straight from int4 components: z' = 16nt + 4quad + r ----
        int bit[4][4];
#pragma unroll
        for (int nt = 0; nt < 4; ++nt) {
            bit[nt][0] = (mc[nt].x > 0) ? 1 : 0;
            bit[nt][1] = (mc[nt].y > 0) ? 1 : 0;
            bit[nt][2] = (mc[nt].z > 0) ? 1 : 0;
            bit[nt][3] = (mc[nt].w > 0) ? 1 : 0;
            cnt += bit[nt][0] + bit[nt][1] + bit[nt][2] + bit[nt][3];
        }

        // ---- masked max: in-lane tree + 2 cross-quad shuffles ----
        float tm = -1e30f;
#pragma unroll
        for (int nt = 0; nt < 4; ++nt) {
            float a0 = bit[nt][0] ? sfr[nt][0] : -1e30f;
            float a1 = bit[nt][1] ? sfr[nt][1] : -1e30f;
            float a2 = bit[nt][2] ? sfr[nt][2] : -1e30f;
            float a3 = bit[nt][3] ? sfr[nt][3] : -1e30f;
            tm = fmaxf(tm, fmaxf(fmaxf(a0, a1), fmaxf(a2, a3)));
        }
        tm = fmaxf(tm, __shfl_xor(tm, 16));
        tm = fmaxf(tm, __shfl_xor(tm, 32));

        // ---- T13 defer-max: only rescale when the max moved by > 8 (base-2) ----
        if (__any(tm > m_s + 8.f)) {
            float mnew = fmaxf(m_s, tm);
            float al = EXP2F(m_s - mnew);     // first active tile: exp2(-huge) = 0
            m_s = mnew;
            l_s *= al;
#pragma unroll
            for (int n = 0; n < 8; ++n) acc2[n] *= al;
        }

        // ---- P = mask ? 2^(S - m) : 0 ; pack to per-wave LDS (B-frag route) ----
        unsigned short* pwv = s_P + wave * (WROWS * SP_STRIDE) + l15 * SP_STRIDE + quad * 4;
        float ps = 0.f;
#pragma unroll
        for (int nt = 0; nt < 4; ++nt) {
            float p0 = bit[nt][0] ? EXP2F(sfr[nt][0] - m_s) : 0.f;
            float p1 = bit[nt][1] ? EXP2F(sfr[nt][1] - m_s) : 0.f;
            float p2 = bit[nt][2] ? EXP2F(sfr[nt][2] - m_s) : 0.f;
            float p3 = bit[nt][3] ? EXP2F(sfr[nt][3] - m_s) : 0.f;
            ps += (p0 + p1) + (p2 + p3);
            ushort4 h;
            h.x = f2bf(p0); h.y = f2bf(p1); h.z = f2bf(p2); h.w = f2bf(p3);
            *(ushort4*)(pwv + nt * 16) = h;   // s_P[b=l15][z' = 16nt + 4quad + 0..3]
        }
        ps += __shfl_xor(ps, 16);
        ps += __shfl_xor(ps, 32);
        l_s += ps;

        // ---- GEMM2 (O^T): acc2[nt2] += embT_rows @ P^T  (K = 64 via two slices) ----
        // same-wave DS ordering guarantees the P writes above are visible to these reads
        const unsigned short* pb = s_P + wave * (WROWS * SP_STRIDE) + l15 * SP_STRIDE + quad * 8;
        bf16x8 pA0 = *(const bf16x8*)(pb);        // P[b=l15][z = quad*8 + j], z<32
        bf16x8 pA1 = *(const bf16x8*)(pb + 32);   // z >= 32
#pragma unroll
        for (int nt2 = 0; nt2 < 8; ++nt2) {
            const unsigned short* tb = s_embT + (nt2 * 16 + l15) * SEMBT_STRIDE + quad * 8;
            bf16x8 e0 = *(const bf16x8*)(tb);
            bf16x8 e1 = *(const bf16x8*)(tb + 32);
            acc2[nt2] = __builtin_amdgcn_mfma_f32_16x16x32_bf16(e0, pA0, acc2[nt2], 0, 0, 0);
            acc2[nt2] = __builtin_amdgcn_mfma_f32_16x16x32_bf16(e1, pA1, acc2[nt2], 0, 0, 0);
        }

#pragma unroll
        for (int nt = 0; nt < 4; ++nt) mc[nt] = mn[nt];
    }

    // ---- epilogue: O rows are lane-local -> 8 vector stores; reduce cnt across quads ----
    {
        float* orow = ws + WS_O + ((size_t)ch * B_SZ + brow) * D_SZ;
#pragma unroll
        for (int nt2 = 0; nt2 < 8; ++nt2) {
            *(f32x4*)(orow + nt2 * 16 + quad * 4) = acc2[nt2];
        }
    }
    cnt += __shfl_xor(cnt, 16);
    cnt += __shfl_xor(cnt, 32);
    if (lane < 16) {
        ws[WS_M + ch * B_SZ + brow] = m_s;
        ws[WS_L + ch * B_SZ + brow] = l_s;
        ws[WS_C + ch * B_SZ + brow] = (float)cnt;
    }
}

__global__ __launch_bounds__(128) void attn_reduce(
    const float* __restrict__ ws, float* __restrict__ out)
{
    const int b = blockIdx.x;
    const int d = threadIdx.x;
    const float* mP = ws + WS_M;
    const float* lP = ws + WS_L;
    const float* cP = ws + WS_C;

    float M = -1e30f;
#pragma unroll
    for (int c = 0; c < NZ; ++c) M = fmaxf(M, mP[c * B_SZ + b]);

    float L = 0.f, C = 0.f, acc = 0.f;
#pragma unroll
    for (int c = 0; c < NZ; ++c) {
        float w = EXP2F(mP[c * B_SZ + b] - M);
        L += lP[c * B_SZ + b] * w;
        C += cP[c * B_SZ + b];
        acc += ws[WS_O + ((size_t)c * B_SZ + b) * D_SZ + d] * w;
    }
    float cntv = fmaxf(C, 1.0f);
    out[(size_t)b * D_SZ + d] = (L > 0.f) ? acc / (L * cntv) : 0.f;
}

extern "C" void kernel_launch(void* const* d_in, const int* in_sizes, int n_in,
                              void* d_out, int out_size, void* d_ws, size_t ws_size,
                              hipStream_t stream) {
    (void)in_sizes; (void)n_in; (void)out_size; (void)ws_size;
    const int*   zs  = (const int*)  d_in[0];
    const float* ctx = (const float*)d_in[1];
    const float* emb = (const float*)d_in[2];
    float* out = (float*)d_out;
    float* ws  = (float*)d_ws;

    unsigned short* embR = (unsigned short*)(ws + WS_TAB);
    unsigned short* embT = embR + (size_t)Z_SZ * D_SZ;

    prep<<<NB_TAB, 256, 0, stream>>>(emb, embR, embT);

    dim3 grid1(B_SZ / TBLK, NZ);   // (8, 64): 512 blocks = 2/CU, 16 waves/CU
    attn_part<<<grid1, 512, 0, stream>>>(zs, ctx, embR, embT, ws);
    attn_reduce<<<B_SZ, 128, 0, stream>>>(ws, out);
}

// Round 8
// 239.712 us; speedup vs baseline: 1.3089x; 1.0341x over previous
//
#include <hip/hip_runtime.h>
#include <stdint.h>

// Problem constants
#define B_SZ 1024
#define Z_SZ 32768
#define D_SZ 128
#define NZ   64                 // z chunks (split-Z)
#define CZ   (Z_SZ / NZ)        // 512 z per chunk
#define TZ   64                 // z per inner tile
#define ITERS (CZ / TZ)         // 8
#define TBLK 128                // batch rows per block (4 waves x 32)
#define NWAVE 4
#define WROWS 32                // batch rows per wave (32x32 MFMA cols)

// LDS strides (elements). Row byte-strides must be 16B multiples for ds_read_b128,
// and every stride must be >= the row's element count.
#define SEMB_STRIDE  136        // 64 x 136 bf16 (row-major emb tile), 272B rows
#define SEMBT_STRIDE 72         // 128 x 72 bf16 (transposed emb tile), 144B rows
#define SP_STRIDE    72         // 32 x 72 bf16 per wave (P tile), 144B rows
#define ST_STRIDE    136        // prep transpose staging rows hold 128 elems

#define NB_TAB  (Z_SZ / 64)     // 512 blocks build bf16 tables

// Workspace layout (float offsets)
#define WS_O   0                              // [NZ][B][D]  (33.5 MB)
#define WS_M   (NZ * B_SZ * D_SZ)             // [NZ][B]
#define WS_L   (WS_M + NZ * B_SZ)
#define WS_C   (WS_L + NZ * B_SZ)
#define WS_TAB (WS_C + NZ * B_SZ)             // embR [Z][D] bf16, embT [D][Z] bf16

typedef short bf16x8  __attribute__((ext_vector_type(8)));
typedef float f32x4   __attribute__((ext_vector_type(4)));
typedef float f32x16  __attribute__((ext_vector_type(16)));

#if __has_builtin(__builtin_amdgcn_exp2f)
#define EXP2F(x) __builtin_amdgcn_exp2f(x)
#else
#define EXP2F(x) exp2f(x)
#endif

__device__ __forceinline__ unsigned short f2bf(float f) {
    union { float f; uint32_t u; } v; v.f = f;
    uint32_t u = v.u;
    u = (u + 0x7FFFu + ((u >> 16) & 1u)) >> 16;   // RNE truncate to bf16
    return (unsigned short)u;
}

// ---------------------------------------------------------------------------
// Prep: emb f32 [Z][D] -> bf16 embR [Z][D] and embT [D][Z]  (one block / 64 z)
// ---------------------------------------------------------------------------
__global__ __launch_bounds__(256) void prep(
    const float*    __restrict__ emb,
    unsigned short* __restrict__ embR,
    unsigned short* __restrict__ embT)
{
    __shared__ __align__(16) unsigned short st[64 * ST_STRIDE];
    const int z0 = blockIdx.x * 64;
    const int t  = threadIdx.x;
    {
        const int r = t >> 2, q = t & 3;
        const float* src = emb + (size_t)(z0 + r) * D_SZ + q * 32;
        unsigned short* dR = embR + (size_t)(z0 + r) * D_SZ + q * 32;
        unsigned short* dL = st + r * ST_STRIDE + q * 32;
#pragma unroll
        for (int u = 0; u < 8; ++u) {
            float4 x = *(const float4*)(src + 4 * u);
            ushort4 h;
            h.x = f2bf(x.x); h.y = f2bf(x.y); h.z = f2bf(x.z); h.w = f2bf(x.w);
            *(ushort4*)(dR + 4 * u) = h;
            *(ushort4*)(dL + 4 * u) = h;
        }
    }
    __syncthreads();
    {
        const int lane = t & 63, w = t >> 6;
#pragma unroll
        for (int i = 0; i < 4; ++i) {
            const int d = w * 32 + i * 8 + (lane >> 3);   // 0..127
            const int c = lane & 7;                       // 8-z chunk
            bf16x8 v;
#pragma unroll
            for (int k = 0; k < 8; ++k) v[k] = (short)st[(c * 8 + k) * ST_STRIDE + d];
            *(bf16x8*)(embT + (size_t)d * Z_SZ + z0 + c * 8) = v;
        }
    }
}

// ---------------------------------------------------------------------------
// attn_part with 32x32x16 MFMA (fat waves: 32 batch rows/wave):
//   GEMM1: sfr[nt] = mfma32(embR_rows, ctx)  -> lane(hi,l31) holds
//          S[b=l31][z' = 32nt + 8*(r>>2) + 4*hi + (r&3)]   (r = reg 0..15)
//   masks: int4 at zs[brow][z0 + 32nt + 8g + 4hi] <-> regs 4g+0..3   (exact)
//   softmax: in-lane over 32 + ONE shfl_xor(32); T13 defer-max (THR=8)
//   GEMM2 (O^T): acc[nt2] = mfma32(embT_rows, P^T) -> lane holds O[d][b=l31]
//   Staging: direct global->LDS (tables L2-hot); masks prefetched (HBM).
// ---------------------------------------------------------------------------
__global__ __launch_bounds__(256, 2) void attn_part(
    const int*            __restrict__ zs,
    const float*          __restrict__ ctx,
    const unsigned short* __restrict__ embR,
    const unsigned short* __restrict__ embT,
    float*                __restrict__ ws)
{
    __shared__ __align__(16) unsigned short s_emb [TZ   * SEMB_STRIDE];       // 17408 B
    __shared__ __align__(16) unsigned short s_embT[D_SZ * SEMBT_STRIDE];      // 18432 B
    __shared__ __align__(16) unsigned short s_P   [NWAVE * WROWS * SP_STRIDE];// 18432 B

    const int tid  = threadIdx.x;
    const int wave = tid >> 6;
    const int lane = tid & 63;
    const int l31  = lane & 31;
    const int hi   = lane >> 5;

    const int bg     = blockIdx.x;            // 0..7 batch group
    const int ch     = blockIdx.y;            // 0..63 z-chunk
    const int z_base = ch * CZ;
    const int wb0    = bg * TBLK + wave * WROWS;  // first batch row of this wave
    const int brow   = wb0 + l31;                 // this lane's batch row (32 rows/wave)

    // staging thread mappings (256 threads, 64B each per tile)
    const int srow = tid >> 2, sq3 = tid & 3;   // row tile: row, 32-elem seg
    const int sd   = tid >> 1, sh  = tid & 1;   // transposed tile: d-row, 32-z seg

    const int* zrow = zs + (size_t)brow * Z_SZ + hi * 4;   // lane's mask base

    // ---- ctx B-fragments, scaled by log2(e)/sqrt(D) (base-2 softmax), in regs ----
    // B-frag for mfma_32x32x16: lane holds B[k = hi*8+j][col = l31] = ctx[brow][ks*16 + k]
    bf16x8 afrag[8];
    {
        const float scale = (float)(1.4426950408889634 * 0.08838834764831845);
        const float* crow = ctx + (size_t)brow * D_SZ;
#pragma unroll
        for (int ks = 0; ks < 8; ++ks) {
            const float* p = crow + ks * 16 + hi * 8;
            float4 x0 = *(const float4*)(p);
            float4 x1 = *(const float4*)(p + 4);
            bf16x8 a;
            a[0] = (short)f2bf(x0.x * scale); a[1] = (short)f2bf(x0.y * scale);
            a[2] = (short)f2bf(x0.z * scale); a[3] = (short)f2bf(x0.w * scale);
            a[4] = (short)f2bf(x1.x * scale); a[5] = (short)f2bf(x1.y * scale);
            a[6] = (short)f2bf(x1.z * scale); a[7] = (short)f2bf(x1.w * scale);
            afrag[ks] = a;
        }
    }

    // ---- per-lane online-softmax state for row b = brow (replicated across hi) ----
    float m_s = -1e30f, l_s = 0.f;
    int   cnt = 0;      // this lane's 32 z'/tile; + partner(hi^1) at epilogue
    f32x16 acc[4];
#pragma unroll
    for (int n = 0; n < 4; ++n) {
#pragma unroll
        for (int e = 0; e < 16; ++e) acc[n][e] = 0.f;
    }

    // ---- mask prefetch (HBM latency): mc = current tile, mn = next ----
    int4 mc[2][4], mn[2][4];
#pragma unroll
    for (int nt = 0; nt < 2; ++nt)
#pragma unroll
        for (int g = 0; g < 4; ++g)
            mc[nt][g] = *(const int4*)(zrow + z_base + nt * 32 + g * 8);

    for (int it = 0; it < ITERS; ++it) {
        const int z0 = z_base + it * TZ;
        __syncthreads();   // previous tile's LDS reads complete

        // ---- direct stage: tables are L2/L3-hot; load + write (64B/thread/tile) ----
        {
            const unsigned short* srcR = embR + (size_t)(z0 + srow) * D_SZ + sq3 * 32;
            unsigned short* dst = s_emb + srow * SEMB_STRIDE + sq3 * 32;
            bf16x8 v0 = *(const bf16x8*)(srcR);      bf16x8 v1 = *(const bf16x8*)(srcR + 8);
            bf16x8 v2 = *(const bf16x8*)(srcR + 16); bf16x8 v3 = *(const bf16x8*)(srcR + 24);
            *(bf16x8*)(dst)      = v0; *(bf16x8*)(dst + 8)  = v1;
            *(bf16x8*)(dst + 16) = v2; *(bf16x8*)(dst + 24) = v3;
        }
        {
            const unsigned short* srcT = embT + (size_t)sd * Z_SZ + z0 + sh * 32;
            unsigned short* dst = s_embT + sd * SEMBT_STRIDE + sh * 32;
            bf16x8 v0 = *(const bf16x8*)(srcT);      bf16x8 v1 = *(const bf16x8*)(srcT + 8);
            bf16x8 v2 = *(const bf16x8*)(srcT + 16); bf16x8 v3 = *(const bf16x8*)(srcT + 24);
            *(bf16x8*)(dst)      = v0; *(bf16x8*)(dst + 8)  = v1;
            *(bf16x8*)(dst + 16) = v2; *(bf16x8*)(dst + 24) = v3;
        }

        __syncthreads();   // staging visible

        // ---- issue next tile's mask loads; latency hides under MFMA/softmax ----
        if (it + 1 < ITERS) {
            const int z0n = z0 + TZ;
#pragma unroll
            for (int nt = 0; nt < 2; ++nt)
#pragma unroll
                for (int g = 0; g < 4; ++g)
                    mn[nt][g] = *(const int4*)(zrow + z0n + nt * 32 + g * 8);
        }

        // ---- GEMM1 (32x32x16): lane gets S[b=l31][z' = 32nt + 8(r>>2) + 4hi + (r&3)] ----
        f32x16 sfr[2];
#pragma unroll
        for (int nt = 0; nt < 2; ++nt) {
            f32x16 c;
#pragma unroll
            for (int e = 0; e < 16; ++e) c[e] = 0.f;
            const unsigned short* bb = s_emb + (nt * 32 + l31) * SEMB_STRIDE + hi * 8;
#pragma unroll
            for (int ks = 0; ks < 8; ++ks) {
                bf16x8 ef = *(const bf16x8*)(bb + ks * 16);
                c = __builtin_amdgcn_mfma_f32_32x32x16_bf16(ef, afrag[ks], c, 0, 0, 0);
            }
            sfr[nt] = c;
        }

        // ---- mask bits: reg r=4g+e of tile nt <-> mc[nt][g] component e ----
        int bit[2][16];
#pragma unroll
        for (int nt = 0; nt < 2; ++nt) {
#pragma unroll
            for (int g = 0; g < 4; ++g) {
                bit[nt][4*g+0] = (mc[nt][g].x > 0) ? 1 : 0;
                bit[nt][4*g+1] = (mc[nt][g].y > 0) ? 1 : 0;
                bit[nt][4*g+2] = (mc[nt][g].z > 0) ? 1 : 0;
                bit[nt][4*g+3] = (mc[nt][g].w > 0) ? 1 : 0;
                cnt += bit[nt][4*g+0] + bit[nt][4*g+1] + bit[nt][4*g+2] + bit[nt][4*g+3];
            }
        }

        // ---- masked max: in-lane tree over 32 + ONE cross-half shuffle ----
        float tm = -1e30f;
#pragma unroll
        for (int nt = 0; nt < 2; ++nt) {
#pragma unroll
            for (int r = 0; r < 16; r += 4) {
                float a0 = bit[nt][r+0] ? sfr[nt][r+0] : -1e30f;
                float a1 = bit[nt][r+1] ? sfr[nt][r+1] : -1e30f;
                float a2 = bit[nt][r+2] ? sfr[nt][r+2] : -1e30f;
                float a3 = bit[nt][r+3] ? sfr[nt][r+3] : -1e30f;
                tm = fmaxf(tm, fmaxf(fmaxf(a0, a1), fmaxf(a2, a3)));
            }
        }
        tm = fmaxf(tm, __shfl_xor(tm, 32));

        // ---- T13 defer-max: only rescale when the max moved by > 8 (base-2) ----
        if (__any(tm > m_s + 8.f)) {
            float mnew = fmaxf(m_s, tm);
            float al = EXP2F(m_s - mnew);     // first active tile: exp2(-huge) = 0
            m_s = mnew;
            l_s *= al;
#pragma unroll
            for (int n = 0; n < 4; ++n)
#pragma unroll
                for (int e = 0; e < 16; ++e) acc[n][e] *= al;
        }

        // ---- P = mask ? 2^(S - m) : 0 ; pack to per-wave LDS (B-frag route) ----
        unsigned short* pwv = s_P + wave * (WROWS * SP_STRIDE) + l31 * SP_STRIDE + hi * 4;
        float ps = 0.f;
#pragma unroll
        for (int nt = 0; nt < 2; ++nt) {
#pragma unroll
            for (int g = 0; g < 4; ++g) {
                float p0 = bit[nt][4*g+0] ? EXP2F(sfr[nt][4*g+0] - m_s) : 0.f;
                float p1 = bit[nt][4*g+1] ? EXP2F(sfr[nt][4*g+1] - m_s) : 0.f;
                float p2 = bit[nt][4*g+2] ? EXP2F(sfr[nt][4*g+2] - m_s) : 0.f;
                float p3 = bit[nt][4*g+3] ? EXP2F(sfr[nt][4*g+3] - m_s) : 0.f;
                ps += (p0 + p1) + (p2 + p3);
                ushort4 h;
                h.x = f2bf(p0); h.y = f2bf(p1); h.z = f2bf(p2); h.w = f2bf(p3);
                *(ushort4*)(pwv + nt * 32 + g * 8) = h;  // z' = 32nt + 8g + 4hi + 0..3
            }
        }
        ps += __shfl_xor(ps, 32);
        l_s += ps;

        // ---- GEMM2 (O^T, 32x32x16): acc[nt2] += embT_rows @ P^T  (K=64, 4 slices) ----
        // same-wave DS ordering guarantees the P writes above are visible to these reads
        const unsigned short* pb = s_P + wave * (WROWS * SP_STRIDE) + l31 * SP_STRIDE + hi * 8;
        bf16x8 pfrag[4];
#pragma unroll
        for (int ks2 = 0; ks2 < 4; ++ks2) pfrag[ks2] = *(const bf16x8*)(pb + ks2 * 16);
#pragma unroll
        for (int nt2 = 0; nt2 < 4; ++nt2) {
            const unsigned short* tb = s_embT + (nt2 * 32 + l31) * SEMBT_STRIDE + hi * 8;
#pragma unroll
            for (int ks2 = 0; ks2 < 4; ++ks2) {
                bf16x8 ta = *(const bf16x8*)(tb + ks2 * 16);
                acc[nt2] = __builtin_amdgcn_mfma_f32_32x32x16_bf16(ta, pfrag[ks2], acc[nt2], 0, 0, 0);
            }
        }

#pragma unroll
        for (int nt = 0; nt < 2; ++nt)
#pragma unroll
            for (int g = 0; g < 4; ++g) mc[nt][g] = mn[nt][g];
    }

    // ---- epilogue: O rows lane-local -> 16 f32x4 stores; cnt from both halves ----
    {
        float* orow = ws + WS_O + ((size_t)ch * B_SZ + brow) * D_SZ;
#pragma unroll
        for (int nt2 = 0; nt2 < 4; ++nt2) {
#pragma unroll
            for (int g = 0; g < 4; ++g) {
                f32x4 v;
                v[0] = acc[nt2][4*g+0]; v[1] = acc[nt2][4*g+1];
                v[2] = acc[nt2][4*g+2]; v[3] = acc[nt2][4*g+3];
                *(f32x4*)(orow + nt2 * 32 + g * 8 + hi * 4) = v;   // d = 32nt2+8g+4hi+0..3
            }
        }
    }
    cnt += __shfl_xor(cnt, 32);
    if (lane < 32) {
        ws[WS_M + ch * B_SZ + brow] = m_s;
        ws[WS_L + ch * B_SZ + brow] = l_s;
        ws[WS_C + ch * B_SZ + brow] = (float)cnt;
    }
}

__global__ __launch_bounds__(128) void attn_reduce(
    const float* __restrict__ ws, float* __restrict__ out)
{
    const int b = blockIdx.x;
    const int d = threadIdx.x;
    const float* mP = ws + WS_M;
    const float* lP = ws + WS_L;
    const float* cP = ws + WS_C;

    float M = -1e30f;
#pragma unroll
    for (int c = 0; c < NZ; ++c) M = fmaxf(M, mP[c * B_SZ + b]);

    float L = 0.f, C = 0.f, acc = 0.f;
#pragma unroll
    for (int c = 0; c < NZ; ++c) {
        float w = EXP2F(mP[c * B_SZ + b] - M);
        L += lP[c * B_SZ + b] * w;
        C += cP[c * B_SZ + b];
        acc += ws[WS_O + ((size_t)c * B_SZ + b) * D_SZ + d] * w;
    }
    float cntv = fmaxf(C, 1.0f);
    out[(size_t)b * D_SZ + d] = (L > 0.f) ? acc / (L * cntv) : 0.f;
}

extern "C" void kernel_launch(void* const* d_in, const int* in_sizes, int n_in,
                              void* d_out, int out_size, void* d_ws, size_t ws_size,
                              hipStream_t stream) {
    (void)in_sizes; (void)n_in; (void)out_size; (void)ws_size;
    const int*   zs  = (const int*)  d_in[0];
    const float* ctx = (const float*)d_in[1];
    const float* emb = (const float*)d_in[2];
    float* out = (float*)d_out;
    float* ws  = (float*)d_ws;

    unsigned short* embR = (unsigned short*)(ws + WS_TAB);
    unsigned short* embT = embR + (size_t)Z_SZ * D_SZ;

    prep<<<NB_TAB, 256, 0, stream>>>(emb, embR, embT);

    dim3 grid1(B_SZ / TBLK, NZ);   // (8, 64): 512 blocks = 2/CU
    attn_part<<<grid1, 256, 0, stream>>>(zs, ctx, embR, embT, ws);
    attn_reduce<<<B_SZ, 128, 0, stream>>>(ws, out);
}

// Round 9
// 236.833 us; speedup vs baseline: 1.3248x; 1.0122x over previous
//
#include <hip/hip_runtime.h>
#include <stdint.h>

// Problem constants
#define B_SZ 1024
#define Z_SZ 32768
#define D_SZ 128
#define NZ   64                 // z chunks (split-Z)
#define CZ   (Z_SZ / NZ)        // 512 z per chunk
#define TZ   64                 // z per inner tile
#define ITERS (CZ / TZ)         // 8
#define TBLK 128                // batch rows per block (4 waves x 32)
#define NWAVE 4
#define WROWS 32                // batch rows per wave (32x32 MFMA cols)

// LDS strides (elements). Row byte-strides must be 16B multiples for ds_read_b128,
// and every stride must be >= the row's element count.
#define SEMB_STRIDE  136        // 64 x 136 bf16 (row-major emb tile), 272B rows
#define SEMBT_STRIDE 72         // 128 x 72 bf16 (transposed emb tile), 144B rows
#define ST_STRIDE    136        // prep transpose staging rows hold 128 elems

#define NB_TAB  (Z_SZ / 64)     // 512 blocks build bf16 tables

// Workspace layout (float offsets)
#define WS_O   0                              // [NZ][B][D]  (33.5 MB)
#define WS_M   (NZ * B_SZ * D_SZ)             // [NZ][B]
#define WS_L   (WS_M + NZ * B_SZ)
#define WS_C   (WS_L + NZ * B_SZ)
#define WS_TAB (WS_C + NZ * B_SZ)             // embR [Z][D] bf16, embT [D][Z] bf16

typedef short bf16x8  __attribute__((ext_vector_type(8)));
typedef float f32x4   __attribute__((ext_vector_type(4)));
typedef float f32x16  __attribute__((ext_vector_type(16)));

#if __has_builtin(__builtin_amdgcn_exp2f)
#define EXP2F(x) __builtin_amdgcn_exp2f(x)
#else
#define EXP2F(x) exp2f(x)
#endif

__device__ __forceinline__ unsigned short f2bf(float f) {
    union { float f; uint32_t u; } v; v.f = f;
    uint32_t u = v.u;
    u = (u + 0x7FFFu + ((u >> 16) & 1u)) >> 16;   // RNE truncate to bf16
    return (unsigned short)u;
}
__device__ __forceinline__ uint32_t packbf(float a, float b) {
    return (uint32_t)f2bf(a) | ((uint32_t)f2bf(b) << 16);
}

// ---------------------------------------------------------------------------
// Prep: emb f32 [Z][D] -> bf16 embR [Z][D] and embT [D][Z]  (one block / 64 z)
// ---------------------------------------------------------------------------
__global__ __launch_bounds__(256) void prep(
    const float*    __restrict__ emb,
    unsigned short* __restrict__ embR,
    unsigned short* __restrict__ embT)
{
    __shared__ __align__(16) unsigned short st[64 * ST_STRIDE];
    const int z0 = blockIdx.x * 64;
    const int t  = threadIdx.x;
    {
        const int r = t >> 2, q = t & 3;
        const float* src = emb + (size_t)(z0 + r) * D_SZ + q * 32;
        unsigned short* dR = embR + (size_t)(z0 + r) * D_SZ + q * 32;
        unsigned short* dL = st + r * ST_STRIDE + q * 32;
#pragma unroll
        for (int u = 0; u < 8; ++u) {
            float4 x = *(const float4*)(src + 4 * u);
            ushort4 h;
            h.x = f2bf(x.x); h.y = f2bf(x.y); h.z = f2bf(x.z); h.w = f2bf(x.w);
            *(ushort4*)(dR + 4 * u) = h;
            *(ushort4*)(dL + 4 * u) = h;
        }
    }
    __syncthreads();
    {
        const int lane = t & 63, w = t >> 6;
#pragma unroll
        for (int i = 0; i < 4; ++i) {
            const int d = w * 32 + i * 8 + (lane >> 3);   // 0..127
            const int c = lane & 7;                       // 8-z chunk
            bf16x8 v;
#pragma unroll
            for (int k = 0; k < 8; ++k) v[k] = (short)st[(c * 8 + k) * ST_STRIDE + d];
            *(bf16x8*)(embT + (size_t)d * Z_SZ + z0 + c * 8) = v;
        }
    }
}

// ---------------------------------------------------------------------------
// attn_part: 32x32x16 MFMA, double-buffered LDS, ONE barrier per tile,
//            in-register P exchange (no s_P LDS round-trip).
//   GEMM1: sfr[nt] = mfma32(embR_rows, ctx)  -> lane(hi,l31) holds
//          S[b=l31][z' = 32nt + 8g + 4hi + e]   (reg r = 4g+e)
//   softmax: in-lane over 32 + ONE shfl_xor(32); T13 defer-max (THR=8)
//   P-frag: pack own 4-z half-groups to bf16 u32s, shfl_xor(32) swaps the
//           partner halves -> full 8-z groups per lane, feeding GEMM2 B-frag.
//   GEMM2 (O^T): acc[nt2] = mfma32(embT_rows, P^T) -> lane holds O[d][b=l31]
// ---------------------------------------------------------------------------
__global__ __launch_bounds__(256, 2) void attn_part(
    const int*            __restrict__ zs,
    const float*          __restrict__ ctx,
    const unsigned short* __restrict__ embR,
    const unsigned short* __restrict__ embT,
    float*                __restrict__ ws)
{
    __shared__ __align__(16) unsigned short s_embA [2][TZ   * SEMB_STRIDE];   // 2x17408 B
    __shared__ __align__(16) unsigned short s_embTA[2][D_SZ * SEMBT_STRIDE];  // 2x18432 B

    const int tid  = threadIdx.x;
    const int lane = tid & 63;
    const int l31  = lane & 31;
    const int hi   = lane >> 5;

    const int bg     = blockIdx.x;            // 0..7 batch group
    const int ch     = blockIdx.y;            // 0..63 z-chunk
    const int z_base = ch * CZ;
    const int wb0    = bg * TBLK + (tid >> 6) * WROWS;
    const int brow   = wb0 + l31;             // this lane's batch row (32 rows/wave)

    // staging thread mappings (256 threads, 64B each per tile)
    const int srow = tid >> 2, sq3 = tid & 3;   // row tile: row, 32-elem seg
    const int sd   = tid >> 1, sh  = tid & 1;   // transposed tile: d-row, 32-z seg

    const int* zrow = zs + (size_t)brow * Z_SZ + hi * 4;   // lane's mask base

    // ---- ctx B-fragments, scaled by log2(e)/sqrt(D) (base-2 softmax), in regs ----
    bf16x8 afrag[8];
    {
        const float scale = (float)(1.4426950408889634 * 0.08838834764831845);
        const float* crow = ctx + (size_t)brow * D_SZ;
#pragma unroll
        for (int ks = 0; ks < 8; ++ks) {
            const float* p = crow + ks * 16 + hi * 8;
            float4 x0 = *(const float4*)(p);
            float4 x1 = *(const float4*)(p + 4);
            bf16x8 a;
            a[0] = (short)f2bf(x0.x * scale); a[1] = (short)f2bf(x0.y * scale);
            a[2] = (short)f2bf(x0.z * scale); a[3] = (short)f2bf(x0.w * scale);
            a[4] = (short)f2bf(x1.x * scale); a[5] = (short)f2bf(x1.y * scale);
            a[6] = (short)f2bf(x1.z * scale); a[7] = (short)f2bf(x1.w * scale);
            afrag[ks] = a;
        }
    }

    // ---- per-lane online-softmax state ----
    float m_s = -1e30f, l_s = 0.f;
    int   cnt = 0;
    f32x16 acc[4];
#pragma unroll
    for (int n = 0; n < 4; ++n)
#pragma unroll
        for (int e = 0; e < 16; ++e) acc[n][e] = 0.f;

    // ---- staging registers (tables) + 2-deep mask prefetch ----
    bf16x8 rA[4], rT[4];
    int4   mc[2][4], mn[2][4];

    // prologue: load tile 0 -> regs; write buf0; load tile 1 -> regs; masks tile 0
    {
        const unsigned short* srcR = embR + (size_t)(z_base + srow) * D_SZ + sq3 * 32;
        const unsigned short* srcT = embT + (size_t)sd * Z_SZ + z_base + sh * 32;
#pragma unroll
        for (int u = 0; u < 4; ++u) { rA[u] = *(const bf16x8*)(srcR + u * 8); }
#pragma unroll
        for (int u = 0; u < 4; ++u) { rT[u] = *(const bf16x8*)(srcT + u * 8); }
#pragma unroll
        for (int nt = 0; nt < 2; ++nt)
#pragma unroll
            for (int g = 0; g < 4; ++g)
                mc[nt][g] = *(const int4*)(zrow + z_base + nt * 32 + g * 8);
    }
    {
        unsigned short* dA = s_embA[0] + srow * SEMB_STRIDE + sq3 * 32;
        unsigned short* dT = s_embTA[0] + sd * SEMBT_STRIDE + sh * 32;
#pragma unroll
        for (int u = 0; u < 4; ++u) *(bf16x8*)(dA + u * 8) = rA[u];
#pragma unroll
        for (int u = 0; u < 4; ++u) *(bf16x8*)(dT + u * 8) = rT[u];
    }
    if (ITERS > 1) {
        const int z1 = z_base + TZ;
        const unsigned short* srcR = embR + (size_t)(z1 + srow) * D_SZ + sq3 * 32;
        const unsigned short* srcT = embT + (size_t)sd * Z_SZ + z1 + sh * 32;
#pragma unroll
        for (int u = 0; u < 4; ++u) { rA[u] = *(const bf16x8*)(srcR + u * 8); }
#pragma unroll
        for (int u = 0; u < 4; ++u) { rT[u] = *(const bf16x8*)(srcT + u * 8); }
    }

    int cur = 0;
    for (int it = 0; it < ITERS; ++it) {
        __syncthreads();   // buf[cur] writes visible; prior reads of buf[cur^1] done

        // ---- issue next tile's mask loads (HBM); consumed NEXT iteration ----
        if (it + 1 < ITERS) {
            const int z0n = z_base + (it + 1) * TZ;
#pragma unroll
            for (int nt = 0; nt < 2; ++nt)
#pragma unroll
                for (int g = 0; g < 4; ++g)
                    mn[nt][g] = *(const int4*)(zrow + z0n + nt * 32 + g * 8);
        }

        const unsigned short* se = s_embA[cur];
        const unsigned short* st_ = s_embTA[cur];

        // ---- GEMM1 (32x32x16): lane gets S[b=l31][z' = 32nt + 8g + 4hi + e] ----
        f32x16 sfr[2];
#pragma unroll
        for (int nt = 0; nt < 2; ++nt) {
            f32x16 c;
#pragma unroll
            for (int e = 0; e < 16; ++e) c[e] = 0.f;
            const unsigned short* bb = se + (nt * 32 + l31) * SEMB_STRIDE + hi * 8;
#pragma unroll
            for (int ks = 0; ks < 8; ++ks) {
                bf16x8 ef = *(const bf16x8*)(bb + ks * 16);
                c = __builtin_amdgcn_mfma_f32_32x32x16_bf16(ef, afrag[ks], c, 0, 0, 0);
            }
            sfr[nt] = c;
        }

        // ---- mask bits: reg r=4g+e of tile nt <-> mc[nt][g] component e ----
        int bit[2][16];
#pragma unroll
        for (int nt = 0; nt < 2; ++nt) {
#pragma unroll
            for (int g = 0; g < 4; ++g) {
                bit[nt][4*g+0] = (mc[nt][g].x > 0) ? 1 : 0;
                bit[nt][4*g+1] = (mc[nt][g].y > 0) ? 1 : 0;
                bit[nt][4*g+2] = (mc[nt][g].z > 0) ? 1 : 0;
                bit[nt][4*g+3] = (mc[nt][g].w > 0) ? 1 : 0;
                cnt += bit[nt][4*g+0] + bit[nt][4*g+1] + bit[nt][4*g+2] + bit[nt][4*g+3];
            }
        }

        // ---- masked max: in-lane tree over 32 + ONE cross-half shuffle ----
        float tm = -1e30f;
#pragma unroll
        for (int nt = 0; nt < 2; ++nt) {
#pragma unroll
            for (int r = 0; r < 16; r += 4) {
                float a0 = bit[nt][r+0] ? sfr[nt][r+0] : -1e30f;
                float a1 = bit[nt][r+1] ? sfr[nt][r+1] : -1e30f;
                float a2 = bit[nt][r+2] ? sfr[nt][r+2] : -1e30f;
                float a3 = bit[nt][r+3] ? sfr[nt][r+3] : -1e30f;
                tm = fmaxf(tm, fmaxf(fmaxf(a0, a1), fmaxf(a2, a3)));
            }
        }
        tm = fmaxf(tm, __shfl_xor(tm, 32));

        // ---- T13 defer-max ----
        if (__any(tm > m_s + 8.f)) {
            float mnew = fmaxf(m_s, tm);
            float al = EXP2F(m_s - mnew);
            m_s = mnew;
            l_s *= al;
#pragma unroll
            for (int n = 0; n < 4; ++n)
#pragma unroll
                for (int e = 0; e < 16; ++e) acc[n][e] *= al;
        }

        // ---- P = mask ? 2^(S-m) : 0 ; pack to u32 bf16-pairs (in-register) ----
        // q[G][w]: G = 4nt+g (8-z group), lane holds half-group offset 4hi
        uint32_t q[8][2];
        float ps = 0.f;
#pragma unroll
        for (int nt = 0; nt < 2; ++nt) {
#pragma unroll
            for (int g = 0; g < 4; ++g) {
                float p0 = bit[nt][4*g+0] ? EXP2F(sfr[nt][4*g+0] - m_s) : 0.f;
                float p1 = bit[nt][4*g+1] ? EXP2F(sfr[nt][4*g+1] - m_s) : 0.f;
                float p2 = bit[nt][4*g+2] ? EXP2F(sfr[nt][4*g+2] - m_s) : 0.f;
                float p3 = bit[nt][4*g+3] ? EXP2F(sfr[nt][4*g+3] - m_s) : 0.f;
                ps += (p0 + p1) + (p2 + p3);
                q[4*nt+g][0] = packbf(p0, p1);
                q[4*nt+g][1] = packbf(p2, p3);
            }
        }
        ps += __shfl_xor(ps, 32);
        l_s += ps;

        // ---- assemble GEMM2 B-frags: swap partner half-groups via shfl_xor(32) ----
        // slice ks2 needs P[b][16ks2 + 8hi + j]: group G=2ks2+hi, both halves.
        bf16x8 pfrag[4];
#pragma unroll
        for (int ks2 = 0; ks2 < 4; ++ks2) {
            uint32_t s0 = hi ? q[2*ks2][0] : q[2*ks2+1][0];   // what partner needs
            uint32_t s1 = hi ? q[2*ks2][1] : q[2*ks2+1][1];
            uint32_t r0 = (uint32_t)__shfl_xor((int)s0, 32);
            uint32_t r1 = (uint32_t)__shfl_xor((int)s1, 32);
            union { uint32_t u[4]; bf16x8 v; } P;
            P.u[0] = hi ? r0 : q[2*ks2][0];     // j=0,1
            P.u[1] = hi ? r1 : q[2*ks2][1];     // j=2,3
            P.u[2] = hi ? q[2*ks2+1][0] : r0;   // j=4,5
            P.u[3] = hi ? q[2*ks2+1][1] : r1;   // j=6,7
            pfrag[ks2] = P.v;
        }

        // ---- GEMM2 (O^T, 32x32x16): acc[nt2] += embT_rows @ P^T ----
#pragma unroll
        for (int nt2 = 0; nt2 < 4; ++nt2) {
            const unsigned short* tb = st_ + (nt2 * 32 + l31) * SEMBT_STRIDE + hi * 8;
#pragma unroll
            for (int ks2 = 0; ks2 < 4; ++ks2) {
                bf16x8 ta = *(const bf16x8*)(tb + ks2 * 16);
                acc[nt2] = __builtin_amdgcn_mfma_f32_32x32x16_bf16(ta, pfrag[ks2], acc[nt2], 0, 0, 0);
            }
        }

        // ---- stage tile it+1 into buf[cur^1]; issue loads for tile it+2 ----
        if (it + 1 < ITERS) {
            unsigned short* dA = s_embA[cur ^ 1] + srow * SEMB_STRIDE + sq3 * 32;
            unsigned short* dT = s_embTA[cur ^ 1] + sd * SEMBT_STRIDE + sh * 32;
#pragma unroll
            for (int u = 0; u < 4; ++u) *(bf16x8*)(dA + u * 8) = rA[u];
#pragma unroll
            for (int u = 0; u < 4; ++u) *(bf16x8*)(dT + u * 8) = rT[u];
            if (it + 2 < ITERS) {
                const int z2 = z_base + (it + 2) * TZ;
                const unsigned short* srcR = embR + (size_t)(z2 + srow) * D_SZ + sq3 * 32;
                const unsigned short* srcT = embT + (size_t)sd * Z_SZ + z2 + sh * 32;
#pragma unroll
                for (int u = 0; u < 4; ++u) { rA[u] = *(const bf16x8*)(srcR + u * 8); }
#pragma unroll
                for (int u = 0; u < 4; ++u) { rT[u] = *(const bf16x8*)(srcT + u * 8); }
            }
        }

#pragma unroll
        for (int nt = 0; nt < 2; ++nt)
#pragma unroll
            for (int g = 0; g < 4; ++g) mc[nt][g] = mn[nt][g];
        cur ^= 1;
    }

    // ---- epilogue ----
    {
        float* orow = ws + WS_O + ((size_t)ch * B_SZ + brow) * D_SZ;
#pragma unroll
        for (int nt2 = 0; nt2 < 4; ++nt2) {
#pragma unroll
            for (int g = 0; g < 4; ++g) {
                f32x4 v;
                v[0] = acc[nt2][4*g+0]; v[1] = acc[nt2][4*g+1];
                v[2] = acc[nt2][4*g+2]; v[3] = acc[nt2][4*g+3];
                *(f32x4*)(orow + nt2 * 32 + g * 8 + hi * 4) = v;   // d = 32nt2+8g+4hi+e
            }
        }
    }
    cnt += __shfl_xor(cnt, 32);
    if (lane < 32) {
        ws[WS_M + ch * B_SZ + brow] = m_s;
        ws[WS_L + ch * B_SZ + brow] = l_s;
        ws[WS_C + ch * B_SZ + brow] = (float)cnt;
    }
}

__global__ __launch_bounds__(128) void attn_reduce(
    const float* __restrict__ ws, float* __restrict__ out)
{
    const int b = blockIdx.x;
    const int d = threadIdx.x;
    const float* mP = ws + WS_M;
    const float* lP = ws + WS_L;
    const float* cP = ws + WS_C;

    float M = -1e30f;
#pragma unroll
    for (int c = 0; c < NZ; ++c) M = fmaxf(M, mP[c * B_SZ + b]);

    float L = 0.f, C = 0.f, acc = 0.f;
#pragma unroll
    for (int c = 0; c < NZ; ++c) {
        float w = EXP2F(mP[c * B_SZ + b] - M);
        L += lP[c * B_SZ + b] * w;
        C += cP[c * B_SZ + b];
        acc += ws[WS_O + ((size_t)c * B_SZ + b) * D_SZ + d] * w;
    }
    float cntv = fmaxf(C, 1.0f);
    out[(size_t)b * D_SZ + d] = (L > 0.f) ? acc / (L * cntv) : 0.f;
}

extern "C" void kernel_launch(void* const* d_in, const int* in_sizes, int n_in,
                              void* d_out, int out_size, void* d_ws, size_t ws_size,
                              hipStream_t stream) {
    (void)in_sizes; (void)n_in; (void)out_size; (void)ws_size;
    const int*   zs  = (const int*)  d_in[0];
    const float* ctx = (const float*)d_in[1];
    const float* emb = (const float*)d_in[2];
    float* out = (float*)d_out;
    float* ws  = (float*)d_ws;

    unsigned short* embR = (unsigned short*)(ws + WS_TAB);
    unsigned short* embT = embR + (size_t)Z_SZ * D_SZ;

    prep<<<NB_TAB, 256, 0, stream>>>(emb, embR, embT);

    dim3 grid1(B_SZ / TBLK, NZ);   // (8, 64): 512 blocks = 2/CU
    attn_part<<<grid1, 256, 0, stream>>>(zs, ctx, embR, embT, ws);
    attn_reduce<<<B_SZ, 128, 0, stream>>>(ws, out);
}